// Round 2
// baseline (292.008 us; speedup 1.0000x reference)
//
#include <hip/hip_runtime.h>
#include <hip/hip_bf16.h>

// Problem constants: B=4, C=512, H=W=64 -> N=4096, CK=64
#define NB 4
#define CC 512
#define NN 4096
#define CKK 64
#define NT 32   // NN/128 j-tiles

typedef _Float16 f16x4 __attribute__((ext_vector_type(4)));
typedef _Float16 f16x8 __attribute__((ext_vector_type(8)));
typedef float    f32x4 __attribute__((ext_vector_type(4)));

// raw barriers with counted waits (no full vmcnt drain in the main loop)
#define BAR()       asm volatile("s_barrier" ::: "memory")
#define BAR_LGKM()  asm volatile("s_waitcnt lgkmcnt(0)\n\ts_barrier" ::: "memory")
#define BAR_VM(n)   asm volatile("s_waitcnt vmcnt(" #n ")\n\ts_barrier" ::: "memory")

// ---------------------------------------------------------------------------
// async global->LDS, 16 B per lane. LDS dest is wave-uniform base + lane*16.
// ---------------------------------------------------------------------------
__device__ __forceinline__ void g2l16(const _Float16* g, _Float16* l) {
    __builtin_amdgcn_global_load_lds(
        (const __attribute__((address_space(1))) void*)g,
        (__attribute__((address_space(3))) void*)l, 16, 0, 0);
}

// Stage a 128-row x 32-col f16 tile (row stride ldg) into LDS [128][32],
// 256 threads (4 waves). Linear layout (used by proj).
__device__ __forceinline__ void stage_tile(const _Float16* __restrict__ g, int ldg,
                                           _Float16* lds, int lane, int wave) {
    #pragma unroll
    for (int r = 0; r < 2; r++) {
        int q = r * 4 + wave;
        int row = q * 16 + (lane >> 2);
        int col = (lane & 3) * 8;
        g2l16(g + (size_t)row * ldg + col, lds + q * 512 + lane * 8);
    }
}

// Stage a 128x32 f16 tile with 512 threads, ONE g2l16 per thread.
// LDS dest stays linear (required by global_load_lds); the GLOBAL source
// column-chunk is pre-permuted by (row>>1)&3 so the stored layout is
// XOR-swizzled. Readers apply the same involution (rd_swz).
__device__ __forceinline__ void stage_swz(const _Float16* __restrict__ g, int ldg,
                                          _Float16* lds, int tid) {
    int row = tid >> 2;
    int scq = (tid & 3) ^ ((row >> 1) & 3);
    g2l16(g + (size_t)row * ldg + scq * 8, lds + tid * 8);
}

__device__ __forceinline__ f16x8 rd_swz(const _Float16* lds, int row, int quad) {
    int q = quad ^ ((row >> 1) & 3);
    return *(const f16x8*)(lds + row * 32 + q * 8);
}

// ---------------------------------------------------------------------------
// K0 "prep": blocks 0..2047 transpose x (fp32 [B][C][N]) -> xT (f16 [B][N][C]);
// blocks 2048..2687 pack Wf/Wg/Wh -> Wall[640][512] f16 + Ball[640] fp32.
// ---------------------------------------------------------------------------
__launch_bounds__(256)
__global__ void prep(const float* __restrict__ x, _Float16* __restrict__ xT,
                     const float* __restrict__ Wf, const float* __restrict__ bf_,
                     const float* __restrict__ Wg, const float* __restrict__ bg_,
                     const float* __restrict__ Wh, const float* __restrict__ bh_,
                     _Float16* __restrict__ Wall, float* __restrict__ Ball) {
    const int N = NN, C = CC;
    int bid = blockIdx.x;
    int t = threadIdx.x;
    if (bid < 2048) {
        int n0 = (bid & 63) << 6;
        int c0 = ((bid >> 6) & 7) << 6;
        int b  = bid >> 9;
        __shared__ float T[64][65];
        const float* xb = x + (size_t)b * C * N;
        #pragma unroll
        for (int r = 0; r < 4; r++) {
            int c = (t >> 4) + 16 * r;
            int n4 = (t & 15) * 4;
            float4 v = *(const float4*)(xb + (size_t)(c0 + c) * N + n0 + n4);
            T[n4 + 0][c] = v.x; T[n4 + 1][c] = v.y; T[n4 + 2][c] = v.z; T[n4 + 3][c] = v.w;
        }
        __syncthreads();
        int n = t >> 2, cb = (t & 3) * 16;
        f16x8 h0, h1;
        #pragma unroll
        for (int i = 0; i < 8; i++) { h0[i] = (_Float16)T[n][cb + i]; h1[i] = (_Float16)T[n][cb + 8 + i]; }
        _Float16* dst = xT + (size_t)b * N * C + (size_t)(n0 + n) * C + c0 + cb;
        *(f16x8*)dst = h0;
        *(f16x8*)(dst + 8) = h1;
    } else {
        int o = bid - 2048;  // 0..639
        const float* src;
        if (o < 64)       src = Wf + (size_t)o * C;
        else if (o < 128) src = Wg + (size_t)(o - 64) * C;
        else              src = Wh + (size_t)(o - 128) * C;
        Wall[(size_t)o * C + t]       = (_Float16)src[t];
        Wall[(size_t)o * C + 256 + t] = (_Float16)src[256 + t];
        if (t == 0)
            Ball[o] = (o < 64) ? bf_[o] : (o < 128 ? bg_[o - 64] : bh_[o - 128]);
    }
}

// ---------------------------------------------------------------------------
// K1: projections, NT MFMA GEMM. Y[o][n] = sum_c Wall[o][c]*xT[n][c] + Ball[o]
// Ft/Gt epilogue vectorized (4 consecutive o per thread -> f16x4 store).
// ---------------------------------------------------------------------------
__launch_bounds__(256)
__global__ void proj_mfma(const _Float16* __restrict__ xT, const _Float16* __restrict__ Wall,
                          const float* __restrict__ Ball,
                          _Float16* __restrict__ Ft, _Float16* __restrict__ Gt,
                          _Float16* __restrict__ Hx) {
    const int N = NN, C = CC;
    int n0 = blockIdx.x * 128;
    int o0 = blockIdx.y * 128;
    int b  = blockIdx.z;
    const _Float16* Arow = Wall + (size_t)o0 * C;
    const _Float16* Brow = xT + (size_t)b * N * C + (size_t)n0 * C;
    __shared__ _Float16 As[128 * 32];
    __shared__ _Float16 Bs[128 * 32];
    int tid = threadIdx.x, lane = tid & 63, wave = tid >> 6;
    int wm = wave & 1, wn = wave >> 1, lrow = lane & 15, quad = lane >> 4;
    f32x4 acc[4][4] = {};
    for (int kc = 0; kc < C; kc += 32) {
        __syncthreads();
        stage_tile(Arow + kc, C, As, lane, wave);
        stage_tile(Brow + kc, C, Bs, lane, wave);
        __syncthreads();
        f16x8 af[4], bf[4];
        #pragma unroll
        for (int mi = 0; mi < 4; mi++)
            af[mi] = *(const f16x8*)(As + (wm * 64 + mi * 16 + lrow) * 32 + quad * 8);
        #pragma unroll
        for (int ni = 0; ni < 4; ni++)
            bf[ni] = *(const f16x8*)(Bs + (wn * 64 + ni * 16 + lrow) * 32 + quad * 8);
        #pragma unroll
        for (int mi = 0; mi < 4; mi++)
            #pragma unroll
            for (int ni = 0; ni < 4; ni++)
                acc[mi][ni] = __builtin_amdgcn_mfma_f32_16x16x32_f16(af[mi], bf[ni], acc[mi][ni], 0, 0, 0);
    }
    float bias_r[4][4];
    #pragma unroll
    for (int mi = 0; mi < 4; mi++)
        #pragma unroll
        for (int r = 0; r < 4; r++)
            bias_r[mi][r] = Ball[o0 + wm * 64 + mi * 16 + quad * 4 + r];
    _Float16* Ftb = Ft + (size_t)b * NN * CKK;
    _Float16* Gtb = Gt + (size_t)b * NN * CKK;
    _Float16* Hxb = Hx + (size_t)b * CC * N;
    #pragma unroll
    for (int mi = 0; mi < 4; mi++)
        #pragma unroll
        for (int ni = 0; ni < 4; ni++) {
            int o = o0 + wm * 64 + mi * 16 + quad * 4;
            int n = n0 + wn * 64 + ni * 16 + lrow;
            f16x4 v;
            #pragma unroll
            for (int r = 0; r < 4; r++) v[r] = (_Float16)(acc[mi][ni][r] + bias_r[mi][r]);
            if (o < 64)       *(f16x4*)(Ftb + (size_t)n * CKK + o) = v;
            else if (o < 128) *(f16x4*)(Gtb + (size_t)n * CKK + (o - 64)) = v;
            else {
                #pragma unroll
                for (int r = 0; r < 4; r++)
                    Hxb[(size_t)(o - 128 + r) * N + n] = v[r];
            }
        }
}

// ---------------------------------------------------------------------------
// K2: fused flash attention, counted-vmcnt pipelined.
// Per j-tile, per thread, 10 async loads issued at iteration top:
//   C0 (Hx k-cols 0..63, 4 loads) -> Ah[0]; C1 (64..127, 4) -> Ah[1];
//   G(jt+1) (2) -> BsG[nxt].
// Waits: BAR_VM(10) retires G(jt) (issued one iteration earlier);
//        BAR_VM(6)/BAR_VM(2) retire C0/C1 (covered by S+softmax compute).
// Softmax: shfl_xor partial reduce -> Mred[128][9]; block-wide skip-rescale
// flag (Osc=1 for rows whose max didn't grow => exact).
// ---------------------------------------------------------------------------
#define PST_LD  136
#define MRL     9
#define SM_FT    0        // 16384
#define SM_BSG   16384    // 32768 (2 x [2ks][128][32])
#define SM_PST   49152    // 34816
#define SM_AH    83968    // 65536 (2 x [2ks2][256][32])
#define SM_MRED  149504   // 4608
#define SM_MRUN  154112
#define SM_LRUN  154624
#define SM_OSC   155136
#define SM_FLAG  155648
#define SM_TOTAL 155776

__launch_bounds__(512, 2)
__global__ void attn_fused(const _Float16* __restrict__ Ft, const _Float16* __restrict__ Gt,
                           const _Float16* __restrict__ Hx, const float* __restrict__ x,
                           const float* __restrict__ gamma, float* __restrict__ out) {
    const int N = NN;
    extern __shared__ char smem[];
    _Float16* FtL  = (_Float16*)(smem + SM_FT);
    _Float16* BsGp = (_Float16*)(smem + SM_BSG);
    _Float16* Pst  = (_Float16*)(smem + SM_PST);
    _Float16* AhL  = (_Float16*)(smem + SM_AH);
    float* Mred = (float*)(smem + SM_MRED);
    float* Mrun = (float*)(smem + SM_MRUN);
    float* Lrun = (float*)(smem + SM_LRUN);
    float* Osc  = (float*)(smem + SM_OSC);
    int*   Fl   = (int*)(smem + SM_FLAG);

    const int b  = blockIdx.z;
    const int i0 = blockIdx.x * 128;
    const int c0 = blockIdx.y * 256;
    const int tid = threadIdx.x;
    const int lane = tid & 63, w = tid >> 6;
    const int lrow = lane & 15, quad = lane >> 4;
    const int wi = w & 3, wj = w >> 2;       // S-phase: 32-row group x 64-col half
    const int wc = w >> 1, wi2 = w & 1;      // PV-phase: 64-c group x 64-i half

    const _Float16* Ftb = Ft + (size_t)b * N * CKK + (size_t)i0 * CKK;
    const _Float16* Gtb = Gt + (size_t)b * N * CKK;
    const _Float16* Hxb = Hx + (size_t)b * CC * N + (size_t)c0 * N;

    // prologue: Ft tile + G(0); one full drain, then steady pipeline
    stage_swz(Ftb,      CKK, FtL,        tid);
    stage_swz(Ftb + 32, CKK, FtL + 4096, tid);
    stage_swz(Gtb,      CKK, BsGp,        tid);
    stage_swz(Gtb + 32, CKK, BsGp + 4096, tid);
    if (tid < 128) { Mrun[tid] = -1e30f; Lrun[tid] = 0.0f; }
    if (tid == 0) Fl[0] = 0;
    __syncthreads();

    f16x8 afs[2][2];
    #pragma unroll
    for (int mi = 0; mi < 2; mi++)
        #pragma unroll
        for (int ks = 0; ks < 2; ks++)
            afs[mi][ks] = rd_swz(FtL + ks * 4096, wi * 32 + mi * 16 + lrow, quad);

    f32x4 acc[4][4] = {};

    #pragma unroll 1
    for (int jt = 0; jt < NT; jt++) {
        const int cur = jt & 1;
        // ---- issue ALL staging for this iteration + next Gt (10 loads) ----
        const _Float16* Hxr = Hxb + (size_t)jt * 128;
        stage_swz(Hxr,                        N, AhL,         tid);
        stage_swz(Hxr + (size_t)128 * N,      N, AhL + 4096,  tid);
        stage_swz(Hxr + 32,                   N, AhL + 8192,  tid);
        stage_swz(Hxr + 32 + (size_t)128 * N, N, AhL + 12288, tid);
        stage_swz(Hxr + 64,                   N, AhL + 16384, tid);
        stage_swz(Hxr + 64 + (size_t)128 * N, N, AhL + 20480, tid);
        stage_swz(Hxr + 96,                   N, AhL + 24576, tid);
        stage_swz(Hxr + 96 + (size_t)128 * N, N, AhL + 28672, tid);
        const _Float16* Gn = Gtb + (size_t)((jt + 1) & (NT - 1)) * 128 * CKK;
        _Float16* Gdst = BsGp + (cur ^ 1) * 8192;
        stage_swz(Gn,      CKK, Gdst,        tid);
        stage_swz(Gn + 32, CKK, Gdst + 4096, tid);
        BAR_VM(10);                               // G(jt) retired -> BsG[cur] ready

        // ---- S = Ft . Gt^T (32i x 64j per wave, K=64) ----
        const _Float16* Bst = BsGp + cur * 8192;
        f32x4 sacc[2][4] = {};
        #pragma unroll
        for (int ks = 0; ks < 2; ks++)
            #pragma unroll
            for (int ni = 0; ni < 4; ni++) {
                f16x8 bfs = rd_swz(Bst + ks * 4096, wj * 64 + ni * 16 + lrow, quad);
                #pragma unroll
                for (int mi = 0; mi < 2; mi++)
                    sacc[mi][ni] = __builtin_amdgcn_mfma_f32_16x16x32_f16(afs[mi][ks], bfs, sacc[mi][ni], 0, 0, 0);
            }
        // ---- row-max: in-thread (4 ni) + 3-level shfl_xor over lrow ----
        float red[8];
        #pragma unroll
        for (int mi = 0; mi < 2; mi++)
            #pragma unroll
            for (int r = 0; r < 4; r++)
                red[mi * 4 + r] = fmaxf(fmaxf(sacc[mi][0][r], sacc[mi][1][r]),
                                        fmaxf(sacc[mi][2][r], sacc[mi][3][r]));
        #pragma unroll
        for (int off = 1; off < 8; off <<= 1)
            #pragma unroll
            for (int s = 0; s < 8; s++)
                red[s] = fmaxf(red[s], __shfl_xor(red[s], off));
        if ((lrow & 7) == 0) {
            #pragma unroll
            for (int mi = 0; mi < 2; mi++)
                #pragma unroll
                for (int r = 0; r < 4; r++)
                    Mred[(wi * 32 + mi * 16 + quad * 4 + r) * MRL + wj * 2 + (lrow >> 3)] = red[mi * 4 + r];
        }
        BAR_LGKM();                               // B2

        // ---- online stats (one thread per row); skip-rescale flag ----
        if (tid < 128) {
            const float* mr = Mred + tid * MRL;
            float mt = mr[0];
            #pragma unroll
            for (int k = 1; k < 8; k++) mt = fmaxf(mt, mr[k]);
            float mo = Mrun[tid];
            if (mt > mo) {
                Fl[0] = 1;
                Mrun[tid] = mt;
                float sc = __expf(mo - mt);
                Osc[tid] = sc;
                Lrun[tid] *= sc;
            } else {
                Osc[tid] = 1.0f;
            }
        }
        BAR_LGKM();                               // B3

        // ---- P' = exp(s - m) -> Pst ; lsum partials via shfl ----
        #pragma unroll
        for (int mi = 0; mi < 2; mi++)
            #pragma unroll
            for (int r = 0; r < 4; r++) {
                int row = wi * 32 + mi * 16 + quad * 4 + r;
                float m = Mrun[row];
                float ls = 0.f;
                #pragma unroll
                for (int ni = 0; ni < 4; ni++) {
                    _Float16 p16 = (_Float16)__expf(sacc[mi][ni][r] - m);
                    Pst[row * PST_LD + wj * 64 + ni * 16 + lrow] = p16;
                    ls += (float)p16;
                }
                red[mi * 4 + r] = ls;
            }
        #pragma unroll
        for (int off = 1; off < 8; off <<= 1)
            #pragma unroll
            for (int s = 0; s < 8; s++)
                red[s] += __shfl_xor(red[s], off);
        if ((lrow & 7) == 0) {
            #pragma unroll
            for (int mi = 0; mi < 2; mi++)
                #pragma unroll
                for (int r = 0; r < 4; r++)
                    Mred[(wi * 32 + mi * 16 + quad * 4 + r) * MRL + wj * 2 + (lrow >> 3)] = red[mi * 4 + r];
        }
        // ---- O-rescale only when some row's max grew (block-uniform flag) ----
        if (Fl[0]) {
            float scv[4];
            #pragma unroll
            for (int ni = 0; ni < 4; ni++) scv[ni] = Osc[wi2 * 64 + ni * 16 + lrow];
            #pragma unroll
            for (int mi = 0; mi < 4; mi++)
                #pragma unroll
                for (int ni = 0; ni < 4; ni++)
                    #pragma unroll
                    for (int r = 0; r < 4; r++)
                        acc[mi][ni][r] *= scv[ni];
        }
        BAR_LGKM();                               // B4: Pst + lsum ready

        if (tid < 128) {
            const float* mr = Mred + tid * MRL;
            float s = 0.f;
            #pragma unroll
            for (int k = 0; k < 8; k++) s += mr[k];
            Lrun[tid] += s;
        }
        if (tid == 0) Fl[0] = 0;

        // ---- PV: two 64-col halves, counted waits (C1/G stay in flight) ----
        auto pv_half = [&](const _Float16* Ab, int kb) {
            #pragma unroll
            for (int ks2 = 0; ks2 < 2; ks2++) {
                f16x8 bfv[4];
                #pragma unroll
                for (int ni = 0; ni < 4; ni++)
                    bfv[ni] = *(const f16x8*)(Pst + (wi2 * 64 + ni * 16 + lrow) * PST_LD + (kb + ks2) * 32 + quad * 8);
                #pragma unroll
                for (int mi = 0; mi < 4; mi++) {
                    f16x8 av = rd_swz(Ab + ks2 * 8192, wc * 64 + mi * 16 + lrow, quad);
                    #pragma unroll
                    for (int ni = 0; ni < 4; ni++)
                        acc[mi][ni] = __builtin_amdgcn_mfma_f32_16x16x32_f16(av, bfv[ni], acc[mi][ni], 0, 0, 0);
                }
            }
        };
        BAR_VM(6);                                // C0 retired
        pv_half(AhL, 0);
        BAR_VM(2);                                // C1 retired (G(jt+1) in flight)
        pv_half(AhL + 16384, 2);
        BAR();                                    // B_end: PV reads done before next writes
    }

    __syncthreads();
    if (tid < 128) Osc[tid] = 1.0f / Lrun[tid];
    __syncthreads();

    float gv = gamma[0];
    const float* xb = x + (size_t)b * CC * N;
    float* ob = out + (size_t)b * CC * N;
    float li[4];
    #pragma unroll
    for (int ni = 0; ni < 4; ni++) li[ni] = Osc[wi2 * 64 + ni * 16 + lrow];
    #pragma unroll
    for (int mi = 0; mi < 4; mi++)
        #pragma unroll
        for (int ni = 0; ni < 4; ni++)
            #pragma unroll
            for (int r = 0; r < 4; r++) {
                int c = c0 + wc * 64 + mi * 16 + quad * 4 + r;
                int i = i0 + wi2 * 64 + ni * 16 + lrow;
                ob[(size_t)c * N + i] = gv * (acc[mi][ni][r] * li[ni]) + xb[(size_t)c * N + i];
            }
}

extern "C" void kernel_launch(void* const* d_in, const int* in_sizes, int n_in,
                              void* d_out, int out_size, void* d_ws, size_t ws_size,
                              hipStream_t stream) {
    const float* x     = (const float*)d_in[0];
    const float* Wf    = (const float*)d_in[1];
    const float* bf    = (const float*)d_in[2];
    const float* Wg    = (const float*)d_in[3];
    const float* bg    = (const float*)d_in[4];
    const float* Wh    = (const float*)d_in[5];
    const float* bh    = (const float*)d_in[6];
    const float* gamma = (const float*)d_in[7];
    float* out = (float*)d_out;

    // Workspace layout (bytes):
    //   Wall [640][512] f16    @ 0        (640 KiB)
    //   Ball [640]      fp32   @ 768 KiB
    //   Ft   [B][N][64] f16    @ 1 MiB    (2 MiB)
    //   Gt   [B][N][64] f16    @ 3 MiB    (2 MiB)
    //   Hx   [B][C][N]  f16    @ 5 MiB    (16 MiB)
    //   xT   [B][N][C]  f16    @ 21 MiB   (17 MiB)
    char* wsb = (char*)d_ws;
    _Float16* Wall = (_Float16*)wsb;
    float*    Ball = (float*)(wsb + ((size_t)768 << 10));
    _Float16* Ft = (_Float16*)(wsb + ((size_t)1 << 20));
    _Float16* Gt = (_Float16*)(wsb + ((size_t)3 << 20));
    _Float16* Hx = (_Float16*)(wsb + ((size_t)5 << 20));
    _Float16* xT = (_Float16*)(wsb + ((size_t)21 << 20));

    static const bool attn_attr_once = [] {
        hipFuncSetAttribute((const void*)attn_fused,
                            hipFuncAttributeMaxDynamicSharedMemorySize, SM_TOTAL);
        return true;
    }();
    (void)attn_attr_once;

    prep<<<dim3(2048 + 640), dim3(256), 0, stream>>>(
        x, xT, Wf, bf, Wg, bg, Wh, bh, Wall, Ball);
    proj_mfma<<<dim3(NN / 128, 5, NB), dim3(256), 0, stream>>>(xT, Wall, Ball, Ft, Gt, Hx);
    attn_fused<<<dim3(NN / 128, CC / 256, NB), dim3(512), SM_TOTAL, stream>>>(
        Ft, Gt, Hx, x, gamma, out);
}

// Round 4
// 290.164 us; speedup vs baseline: 1.0064x; 1.0064x over previous
//
#include <hip/hip_runtime.h>
#include <hip/hip_bf16.h>

// Problem constants: B=4, C=512, H=W=64 -> N=4096, CK=64
#define NB 4
#define CC 512
#define NN 4096
#define CKK 64
#define NT 32   // NN/128 j-tiles

typedef _Float16 f16x4 __attribute__((ext_vector_type(4)));
typedef _Float16 f16x8 __attribute__((ext_vector_type(8)));
typedef float    f32x4 __attribute__((ext_vector_type(4)));

// ---------------------------------------------------------------------------
// async global->LDS, 16 B per lane. LDS dest is wave-uniform base + lane*16.
// ---------------------------------------------------------------------------
__device__ __forceinline__ void g2l16(const _Float16* g, _Float16* l) {
    __builtin_amdgcn_global_load_lds(
        (const __attribute__((address_space(1))) void*)g,
        (__attribute__((address_space(3))) void*)l, 16, 0, 0);
}

// Stage a 128-row x 32-col f16 tile (row stride ldg) into LDS [128][32],
// 256 threads (4 waves). Linear layout (used by proj).
__device__ __forceinline__ void stage_tile(const _Float16* __restrict__ g, int ldg,
                                           _Float16* lds, int lane, int wave) {
    #pragma unroll
    for (int r = 0; r < 2; r++) {
        int q = r * 4 + wave;
        int row = q * 16 + (lane >> 2);
        int col = (lane & 3) * 8;
        g2l16(g + (size_t)row * ldg + col, lds + q * 512 + lane * 8);
    }
}

// Stage a 128x32 f16 tile with 512 threads, ONE g2l16 per thread.
// LDS dest stays linear (required by global_load_lds); the GLOBAL source
// column-chunk is pre-permuted by (row>>1)&3 so the stored layout is
// XOR-swizzled. Readers apply the same involution (rd_swz).
__device__ __forceinline__ void stage_swz(const _Float16* __restrict__ g, int ldg,
                                          _Float16* lds, int tid) {
    int row = tid >> 2;
    int scq = (tid & 3) ^ ((row >> 1) & 3);
    g2l16(g + (size_t)row * ldg + scq * 8, lds + tid * 8);
}

__device__ __forceinline__ f16x8 rd_swz(const _Float16* lds, int row, int quad) {
    int q = quad ^ ((row >> 1) & 3);
    return *(const f16x8*)(lds + row * 32 + q * 8);
}

// Stage a 64x64 f16 tile (row stride ldg) with 512 threads; 8 chunks/row,
// chunk XOR row&7 swizzle (2-way max on reads).
__device__ __forceinline__ void stage_ft(const _Float16* __restrict__ g, int ldg,
                                         _Float16* lds, int tid) {
    int row = tid >> 3;
    int ch = (tid & 7) ^ (row & 7);
    g2l16(g + (size_t)row * ldg + ch * 8, lds + tid * 8);
}

__device__ __forceinline__ f16x8 rd_ft(const _Float16* lds, int row, int qq) {
    int ch = qq ^ (row & 7);
    return *(const f16x8*)(lds + row * 64 + ch * 8);
}

// ---------------------------------------------------------------------------
// K0 "prep": blocks 0..2047 transpose x (fp32 [B][C][N]) -> xT (f16 [B][N][C]);
// blocks 2048..2687 pack Wf/Wg/Wh -> Wall[640][512] f16 + Ball[640] fp32.
// ---------------------------------------------------------------------------
__launch_bounds__(256)
__global__ void prep(const float* __restrict__ x, _Float16* __restrict__ xT,
                     const float* __restrict__ Wf, const float* __restrict__ bf_,
                     const float* __restrict__ Wg, const float* __restrict__ bg_,
                     const float* __restrict__ Wh, const float* __restrict__ bh_,
                     _Float16* __restrict__ Wall, float* __restrict__ Ball) {
    const int N = NN, C = CC;
    int bid = blockIdx.x;
    int t = threadIdx.x;
    if (bid < 2048) {
        int n0 = (bid & 63) << 6;
        int c0 = ((bid >> 6) & 7) << 6;
        int b  = bid >> 9;
        __shared__ float T[64][65];
        const float* xb = x + (size_t)b * C * N;
        #pragma unroll
        for (int r = 0; r < 4; r++) {
            int c = (t >> 4) + 16 * r;
            int n4 = (t & 15) * 4;
            float4 v = *(const float4*)(xb + (size_t)(c0 + c) * N + n0 + n4);
            T[n4 + 0][c] = v.x; T[n4 + 1][c] = v.y; T[n4 + 2][c] = v.z; T[n4 + 3][c] = v.w;
        }
        __syncthreads();
        int n = t >> 2, cb = (t & 3) * 16;
        f16x8 h0, h1;
        #pragma unroll
        for (int i = 0; i < 8; i++) { h0[i] = (_Float16)T[n][cb + i]; h1[i] = (_Float16)T[n][cb + 8 + i]; }
        _Float16* dst = xT + (size_t)b * N * C + (size_t)(n0 + n) * C + c0 + cb;
        *(f16x8*)dst = h0;
        *(f16x8*)(dst + 8) = h1;
    } else {
        int o = bid - 2048;  // 0..639
        const float* src;
        if (o < 64)       src = Wf + (size_t)o * C;
        else if (o < 128) src = Wg + (size_t)(o - 64) * C;
        else              src = Wh + (size_t)(o - 128) * C;
        Wall[(size_t)o * C + t]       = (_Float16)src[t];
        Wall[(size_t)o * C + 256 + t] = (_Float16)src[256 + t];
        if (t == 0)
            Ball[o] = (o < 64) ? bf_[o] : (o < 128 ? bg_[o - 64] : bh_[o - 128]);
    }
}

// ---------------------------------------------------------------------------
// K1: projections, NT MFMA GEMM. Y[o][n] = sum_c Wall[o][c]*xT[n][c] + Ball[o]
// Ft/Gt epilogue vectorized (4 consecutive o per thread -> f16x4 store).
// ---------------------------------------------------------------------------
__launch_bounds__(256)
__global__ void proj_mfma(const _Float16* __restrict__ xT, const _Float16* __restrict__ Wall,
                          const float* __restrict__ Ball,
                          _Float16* __restrict__ Ft, _Float16* __restrict__ Gt,
                          _Float16* __restrict__ Hx) {
    const int N = NN, C = CC;
    int n0 = blockIdx.x * 128;
    int o0 = blockIdx.y * 128;
    int b  = blockIdx.z;
    const _Float16* Arow = Wall + (size_t)o0 * C;
    const _Float16* Brow = xT + (size_t)b * N * C + (size_t)n0 * C;
    __shared__ _Float16 As[128 * 32];
    __shared__ _Float16 Bs[128 * 32];
    int tid = threadIdx.x, lane = tid & 63, wave = tid >> 6;
    int wm = wave & 1, wn = wave >> 1, lrow = lane & 15, quad = lane >> 4;
    f32x4 acc[4][4] = {};
    for (int kc = 0; kc < C; kc += 32) {
        __syncthreads();
        stage_tile(Arow + kc, C, As, lane, wave);
        stage_tile(Brow + kc, C, Bs, lane, wave);
        __syncthreads();
        f16x8 af[4], bf[4];
        #pragma unroll
        for (int mi = 0; mi < 4; mi++)
            af[mi] = *(const f16x8*)(As + (wm * 64 + mi * 16 + lrow) * 32 + quad * 8);
        #pragma unroll
        for (int ni = 0; ni < 4; ni++)
            bf[ni] = *(const f16x8*)(Bs + (wn * 64 + ni * 16 + lrow) * 32 + quad * 8);
        #pragma unroll
        for (int mi = 0; mi < 4; mi++)
            #pragma unroll
            for (int ni = 0; ni < 4; ni++)
                acc[mi][ni] = __builtin_amdgcn_mfma_f32_16x16x32_f16(af[mi], bf[ni], acc[mi][ni], 0, 0, 0);
    }
    float bias_r[4][4];
    #pragma unroll
    for (int mi = 0; mi < 4; mi++)
        #pragma unroll
        for (int r = 0; r < 4; r++)
            bias_r[mi][r] = Ball[o0 + wm * 64 + mi * 16 + quad * 4 + r];
    _Float16* Ftb = Ft + (size_t)b * NN * CKK;
    _Float16* Gtb = Gt + (size_t)b * NN * CKK;
    _Float16* Hxb = Hx + (size_t)b * CC * N;
    #pragma unroll
    for (int mi = 0; mi < 4; mi++)
        #pragma unroll
        for (int ni = 0; ni < 4; ni++) {
            int o = o0 + wm * 64 + mi * 16 + quad * 4;
            int n = n0 + wn * 64 + ni * 16 + lrow;
            f16x4 v;
            #pragma unroll
            for (int r = 0; r < 4; r++) v[r] = (_Float16)(acc[mi][ni][r] + bias_r[mi][r]);
            if (o < 64)       *(f16x4*)(Ftb + (size_t)n * CKK + o) = v;
            else if (o < 128) *(f16x4*)(Gtb + (size_t)n * CKK + (o - 64)) = v;
            else {
                #pragma unroll
                for (int r = 0; r < 4; r++)
                    Hxb[(size_t)(o - 128 + r) * N + n] = v[r];
            }
        }
}

// ---------------------------------------------------------------------------
// K2: fused flash attention, occupancy-first variant.
// Block: i-tile 64 x c-tile 256, 512 threads, grid (64,2,4)=512 blocks.
// LDS = 72.7 KB -> 2 blocks/CU (16 waves/CU): the co-resident block's waves
// fill every barrier/vmcnt-drain bubble (m114-style implicit overlap) --
// the lever that manual counted-vmcnt pipelining failed to provide.
// Per j-tile: S = Ft.Gt^T (8 MFMA/wave), online softmax (Mred hybrid
// shfl+LDS reduce), P' -> Pst (LDS only), PV vs 4 Hx chunks (Ah dbuf).
// S-phase waves:  wi=w&1 (32 i), wj=w>>1 (32 j of 128)
// PV-phase waves: wc=w>>1 (64 c of 256), wi2=w&1 (32 i of 64)
// ---------------------------------------------------------------------------
#define PST_LD  136
#define MRL     21
#define SM_AH    0         // 32768: 2 x [256][32] chunk dbuf; FtL aliases buf0
#define SM_BSG   32768     // 16384: [2ks][128][32]
#define SM_PST   49152     // 17408: [64][136]
#define SM_MRED  66560     // 5376:  [64][21] f32
#define SM_MRUN  71936     // 256
#define SM_LRUN  72192     // 256
#define SM_OSC   72448     // 256
#define SM_TOTAL 72704

__launch_bounds__(512, 4)
__global__ void attn_fused(const _Float16* __restrict__ Ft, const _Float16* __restrict__ Gt,
                           const _Float16* __restrict__ Hx, const float* __restrict__ x,
                           const float* __restrict__ gamma, float* __restrict__ out) {
    const int N = NN;
    extern __shared__ char smem[];
    _Float16* AhL = (_Float16*)(smem + SM_AH);
    _Float16* BsG = (_Float16*)(smem + SM_BSG);
    _Float16* Pst = (_Float16*)(smem + SM_PST);
    float* Mred = (float*)(smem + SM_MRED);
    float* Mrun = (float*)(smem + SM_MRUN);
    float* Lrun = (float*)(smem + SM_LRUN);
    float* Osc  = (float*)(smem + SM_OSC);

    const int b  = blockIdx.z;
    const int i0 = blockIdx.x * 64;
    const int c0 = blockIdx.y * 256;
    const int tid = threadIdx.x;
    const int lane = tid & 63, w = tid >> 6;
    const int lrow = lane & 15, quad = lane >> 4;
    const int wi = w & 1, wj = w >> 1;       // S-phase
    const int wc = w >> 1, wi2 = w & 1;      // PV-phase

    const _Float16* Ftb = Ft + (size_t)b * N * CKK + (size_t)i0 * CKK;
    const _Float16* Gtb = Gt + (size_t)b * N * CKK;
    const _Float16* Hxb = Hx + (size_t)b * CC * N + (size_t)c0 * N;

    // prologue: Ft tile (64x64, into Ah buf0 -- dead before PV) + G(0)
    stage_ft(Ftb, CKK, AhL, tid);
    stage_swz(Gtb,      CKK, BsG,        tid);
    stage_swz(Gtb + 32, CKK, BsG + 4096, tid);
    if (tid < 64) { Mrun[tid] = -1e30f; Lrun[tid] = 0.0f; }
    __syncthreads();

    f16x8 afs[2][2];
    #pragma unroll
    for (int mi = 0; mi < 2; mi++)
        #pragma unroll
        for (int ks = 0; ks < 2; ks++)
            afs[mi][ks] = rd_ft(AhL, wi * 32 + mi * 16 + lrow, ks * 4 + quad);

    f32x4 acc[4][2] = {};

    #pragma unroll 1
    for (int jt = 0; jt < NT; jt++) {
        __syncthreads();                          // (A) BsG(jt) ready; prev PV done
        // ---- S = Ft . Gt^T (32i x 32j per wave, K=64) ----
        f32x4 sacc[2][2] = {};
        #pragma unroll
        for (int ks = 0; ks < 2; ks++) {
            f16x8 bq[2];
            #pragma unroll
            for (int nj = 0; nj < 2; nj++)
                bq[nj] = rd_swz(BsG + ks * 4096, wj * 32 + nj * 16 + lrow, quad);
            #pragma unroll
            for (int mi = 0; mi < 2; mi++)
                #pragma unroll
                for (int nj = 0; nj < 2; nj++)
                    sacc[mi][nj] = __builtin_amdgcn_mfma_f32_16x16x32_f16(afs[mi][ks], bq[nj], sacc[mi][nj], 0, 0, 0);
        }
        // ---- issue Ah chunk kk=0 (buf0 free since prev iter; covered to (E0)) ----
        const _Float16* Hxr = Hxb + (size_t)jt * 128;
        stage_swz(Hxr,                   N, AhL,        tid);
        stage_swz(Hxr + (size_t)128 * N, N, AhL + 4096, tid);
        // ---- row-max partials: in-thread (2 nj) + 2-level shfl over lrow&3 ----
        float red[8];
        #pragma unroll
        for (int mi = 0; mi < 2; mi++)
            #pragma unroll
            for (int r = 0; r < 4; r++)
                red[mi * 4 + r] = fmaxf(sacc[mi][0][r], sacc[mi][1][r]);
        #pragma unroll
        for (int off = 1; off < 4; off <<= 1)
            #pragma unroll
            for (int s = 0; s < 8; s++)
                red[s] = fmaxf(red[s], __shfl_xor(red[s], off));
        if ((lrow & 3) == 0) {
            #pragma unroll
            for (int mi = 0; mi < 2; mi++)
                #pragma unroll
                for (int r = 0; r < 4; r++)
                    Mred[(wi * 32 + mi * 16 + quad * 4 + r) * MRL + wj * 4 + (lrow >> 2)] = red[mi * 4 + r];
        }
        __syncthreads();                          // (B) all S reads + Mred done
        // ---- prefetch BsG(jt+1): single buffer, safe after (B) ----
        {
            const _Float16* Gn = Gtb + (size_t)((jt + 1) & (NT - 1)) * 128 * CKK;
            stage_swz(Gn,      CKK, BsG,        tid);
            stage_swz(Gn + 32, CKK, BsG + 4096, tid);
        }
        // ---- online stats (one thread per row) ----
        if (tid < 64) {
            const float* mr = Mred + tid * MRL;
            float mt = mr[0];
            #pragma unroll
            for (int k = 1; k < 16; k++) mt = fmaxf(mt, mr[k]);
            float mo = Mrun[tid];
            float mn = fmaxf(mo, mt);
            float sc = __expf(mo - mn);   // first tile: exp(-inf) = 0
            Mrun[tid] = mn;
            Osc[tid] = sc;
            Lrun[tid] *= sc;
        }
        __syncthreads();                          // (C)
        // ---- P' = exp(s - m) -> Pst ; lsum partials ; acc rescale ----
        #pragma unroll
        for (int mi = 0; mi < 2; mi++)
            #pragma unroll
            for (int r = 0; r < 4; r++) {
                int row = wi * 32 + mi * 16 + quad * 4 + r;
                float m = Mrun[row];
                float ls = 0.f;
                #pragma unroll
                for (int nj = 0; nj < 2; nj++) {
                    _Float16 p16 = (_Float16)__expf(sacc[mi][nj][r] - m);
                    Pst[row * PST_LD + wj * 32 + nj * 16 + lrow] = p16;
                    ls += (float)p16;
                }
                red[mi * 4 + r] = ls;
            }
        #pragma unroll
        for (int off = 1; off < 4; off <<= 1)
            #pragma unroll
            for (int s = 0; s < 8; s++)
                red[s] += __shfl_xor(red[s], off);
        if ((lrow & 3) == 0) {
            #pragma unroll
            for (int mi = 0; mi < 2; mi++)
                #pragma unroll
                for (int r = 0; r < 4; r++)
                    Mred[(wi * 32 + mi * 16 + quad * 4 + r) * MRL + wj * 4 + (lrow >> 2)] = red[mi * 4 + r];
        }
        {
            float scv[2];
            #pragma unroll
            for (int ni = 0; ni < 2; ni++) scv[ni] = Osc[wi2 * 32 + ni * 16 + lrow];
            #pragma unroll
            for (int mi = 0; mi < 4; mi++)
                #pragma unroll
                for (int ni = 0; ni < 2; ni++)
                    #pragma unroll
                    for (int r = 0; r < 4; r++)
                        acc[mi][ni][r] *= scv[ni];
        }
        __syncthreads();                          // (D) Pst + lsum partials ready
        if (tid < 64) {
            const float* mr = Mred + tid * MRL;
            float s = 0.f;
            #pragma unroll
            for (int k = 0; k < 16; k++) s += mr[k];
            Lrun[tid] += s;
        }
        // ---- PV: 4 Hx k-chunks, Ah dbuf; stage(kk+1) issued AFTER the sync
        //      that proves all waves finished reading that buffer ----
        #pragma unroll
        for (int kk = 0; kk < 4; kk++) {
            __syncthreads();                      // (E..H) Ah[kk&1] staged & safe
            if (kk < 3) {
                const _Float16* src = Hxr + (kk + 1) * 32;
                _Float16* dst = AhL + ((kk + 1) & 1) * 8192;
                stage_swz(src,                   N, dst,        tid);
                stage_swz(src + (size_t)128 * N, N, dst + 4096, tid);
            }
            const _Float16* A = AhL + (kk & 1) * 8192;
            f16x8 bfv[2];
            #pragma unroll
            for (int ni = 0; ni < 2; ni++)
                bfv[ni] = *(const f16x8*)(Pst + (wi2 * 32 + ni * 16 + lrow) * PST_LD + kk * 32 + quad * 8);
            #pragma unroll
            for (int mi = 0; mi < 4; mi++) {
                f16x8 av = rd_swz(A, wc * 64 + mi * 16 + lrow, quad);
                #pragma unroll
                for (int ni = 0; ni < 2; ni++)
                    acc[mi][ni] = __builtin_amdgcn_mfma_f32_16x16x32_f16(av, bfv[ni], acc[mi][ni], 0, 0, 0);
            }
        }
    }

    __syncthreads();
    if (tid < 64) Osc[tid] = 1.0f / Lrun[tid];
    __syncthreads();

    float gv = gamma[0];
    const float* xb = x + (size_t)b * CC * N;
    float* ob = out + (size_t)b * CC * N;
    float li[2];
    #pragma unroll
    for (int ni = 0; ni < 2; ni++) li[ni] = Osc[wi2 * 32 + ni * 16 + lrow];
    #pragma unroll
    for (int mi = 0; mi < 4; mi++)
        #pragma unroll
        for (int ni = 0; ni < 2; ni++)
            #pragma unroll
            for (int r = 0; r < 4; r++) {
                int c = c0 + wc * 64 + mi * 16 + quad * 4 + r;
                int i = i0 + wi2 * 32 + ni * 16 + lrow;
                ob[(size_t)c * N + i] = gv * (acc[mi][ni][r] * li[ni]) + xb[(size_t)c * N + i];
            }
}

extern "C" void kernel_launch(void* const* d_in, const int* in_sizes, int n_in,
                              void* d_out, int out_size, void* d_ws, size_t ws_size,
                              hipStream_t stream) {
    const float* x     = (const float*)d_in[0];
    const float* Wf    = (const float*)d_in[1];
    const float* bf    = (const float*)d_in[2];
    const float* Wg    = (const float*)d_in[3];
    const float* bg    = (const float*)d_in[4];
    const float* Wh    = (const float*)d_in[5];
    const float* bh    = (const float*)d_in[6];
    const float* gamma = (const float*)d_in[7];
    float* out = (float*)d_out;

    // Workspace layout (bytes):
    //   Wall [640][512] f16    @ 0        (640 KiB)
    //   Ball [640]      fp32   @ 768 KiB
    //   Ft   [B][N][64] f16    @ 1 MiB    (2 MiB)
    //   Gt   [B][N][64] f16    @ 3 MiB    (2 MiB)
    //   Hx   [B][C][N]  f16    @ 5 MiB    (16 MiB)
    //   xT   [B][N][C]  f16    @ 21 MiB   (17 MiB)
    char* wsb = (char*)d_ws;
    _Float16* Wall = (_Float16*)wsb;
    float*    Ball = (float*)(wsb + ((size_t)768 << 10));
    _Float16* Ft = (_Float16*)(wsb + ((size_t)1 << 20));
    _Float16* Gt = (_Float16*)(wsb + ((size_t)3 << 20));
    _Float16* Hx = (_Float16*)(wsb + ((size_t)5 << 20));
    _Float16* xT = (_Float16*)(wsb + ((size_t)21 << 20));

    static const bool attn_attr_once = [] {
        hipFuncSetAttribute((const void*)attn_fused,
                            hipFuncAttributeMaxDynamicSharedMemorySize, SM_TOTAL);
        return true;
    }();
    (void)attn_attr_once;

    prep<<<dim3(2048 + 640), dim3(256), 0, stream>>>(
        x, xT, Wf, bf, Wg, bg, Wh, bh, Wall, Ball);
    proj_mfma<<<dim3(NN / 128, 5, NB), dim3(256), 0, stream>>>(xT, Wall, Ball, Ft, Gt, Hx);
    attn_fused<<<dim3(NN / 64, CC / 256, NB), dim3(512), SM_TOTAL, stream>>>(
        Ft, Gt, Hx, x, gamma, out);
}